// Round 2
// baseline (450.221 us; speedup 1.0000x reference)
//
#include <hip/hip_runtime.h>

// ClassTokenNested: packed ragged class-token prepend.
// out[(i + seg[i] + 1)] = x[i]   for each input token row i
// out[(lower_bound(seg, s) + s)] = weight   for each segment s
// The map is a bijection onto [0, T+B) output rows, so every row is
// written exactly once and no zero-init is required.

constexpr int DTOK = 256;          // dim_token (fixed by the reference)
constexpr int V4   = DTOK / 4;     // 64 float4 per row == one wave's lanes

// One float4 per lane; a 64-lane wave covers exactly one row, so all
// lanes of a wave read the same seg[row] (L1/L2 broadcast) and the
// 1 KB row write is a single coalesced burst.
__global__ __launch_bounds__(256) void ctn_copy_tokens(
    const float4* __restrict__ x,
    const int* __restrict__ seg,
    float4* __restrict__ out,
    long long total_vec)           // T * V4
{
    long long stride = (long long)gridDim.x * blockDim.x;
    for (long long idx = (long long)blockIdx.x * blockDim.x + threadIdx.x;
         idx < total_vec; idx += stride) {
        int row = (int)(idx >> 6);           // V4 == 64
        int col = (int)(idx & (V4 - 1));
        int s   = seg[row];                  // wave-uniform, cache broadcast
        float4 v = x[idx];
        long long orow = (long long)row + s + 1;
        out[orow * V4 + col] = v;
    }
}

// One wave per segment: redundant per-lane binary search (18 steps over
// sorted seg_ids, L2-resident), then lanes write weight's 64 float4.
__global__ __launch_bounds__(256) void ctn_class_tokens(
    const float4* __restrict__ w,
    const int* __restrict__ seg,
    float4* __restrict__ out,
    int T, int B)
{
    int gid  = blockIdx.x * blockDim.x + threadIdx.x;
    int s    = gid >> 6;
    int lane = gid & 63;
    if (s >= B) return;
    // lower_bound: first index with seg[idx] >= s
    int lo = 0, hi = T;
    while (lo < hi) {
        int mid = (lo + hi) >> 1;
        if (seg[mid] < s) lo = mid + 1; else hi = mid;
    }
    long long orow = (long long)lo + s;      // class_idx = offsets[s] + s
    out[orow * V4 + lane] = w[lane];
}

extern "C" void kernel_launch(void* const* d_in, const int* in_sizes, int n_in,
                              void* d_out, int out_size, void* d_ws, size_t ws_size,
                              hipStream_t stream) {
    const float* x_flat = (const float*)d_in[0];
    const float* weight = (const float*)d_in[1];
    const int*   seg    = (const int*)d_in[2];
    // num_segments (d_in[3]) is a device scalar; derive B from sizes instead
    // (graph-capture safe, no readback):
    int T = in_sizes[2];                     // seg_ids element count
    int B = out_size / DTOK - T;             // out rows = T + B

    float* out = (float*)d_out;

    // Kernel A: token rows. 2048 blocks x 256 threads, grid-stride.
    long long total_vec = (long long)T * V4;
    int blkA = 2048;
    ctn_copy_tokens<<<blkA, 256, 0, stream>>>(
        (const float4*)x_flat, seg, (float4*)out, total_vec);

    // Kernel B: class-token rows. One wave per segment.
    int blkB = (B * 64 + 255) / 256;
    ctn_class_tokens<<<blkB, 256, 0, stream>>>(
        (const float4*)weight, seg, (float4*)out, T, B);
}

// Round 4
// 425.551 us; speedup vs baseline: 1.0580x; 1.0580x over previous
//
#include <hip/hip_runtime.h>

// ClassTokenNested: packed ragged class-token prepend — single fused kernel.
//
// Forward map (bijection onto [0, T+B) output rows, so no zero-init):
//   token row i          -> out row  i + seg[i] + 1
//   class token of seg t -> out row  offsets[t] + t,  offsets[t] = lower_bound(seg, t)
//
// Fusion trick: the wave handling input row i knows offsets[t] == i exactly
// for every segment t in (seg[i-1], seg[i]]  (covers empty segments too),
// so it writes those class tokens at out rows (i + t) with zero searching.
// Row 0 covers t in [0, seg[0]]; the row T-1 wave covers trailing segments
// t in (seg[T-1], B) at out rows (T + t).

constexpr int DTOK = 256;        // dim_token (fixed by the reference)
constexpr int V4   = DTOK / 4;   // 64 float4 per row == one wave

// native clang vector — __builtin_nontemporal_* requires this, not
// HIP_vector_type<float,4>
typedef float f4 __attribute__((ext_vector_type(4)));

__global__ __launch_bounds__(256) void ctn_fused(
    const f4* __restrict__ x,
    const int* __restrict__ seg,
    const f4* __restrict__ w,
    f4*       __restrict__ out,
    int T, int B)
{
    const int lane = threadIdx.x & 63;
    const int wid  = (blockIdx.x * blockDim.x + threadIdx.x) >> 6;
    const int nw   = (gridDim.x * blockDim.x) >> 6;

    const f4 wv = w[lane];   // class-token fragment, held in registers

    for (int row = wid; row < T; row += nw) {
        const int s = seg[row];                       // wave-uniform (broadcast)
        // token row: fully coalesced 1 KB read + 1 KB write, streaming
        const f4 v = __builtin_nontemporal_load(&x[row * V4 + lane]);
        __builtin_nontemporal_store(v, &out[(row + s + 1) * V4 + lane]);

        const int sp = (row == 0) ? -1 : seg[row - 1]; // L1-hot neighbor load
        // class tokens for segments (sp, s] — offsets[t] == row for these
        for (int t = sp + 1; t <= s; ++t)              // wave-uniform loop
            __builtin_nontemporal_store(wv, &out[(row + t) * V4 + lane]);

        if (row == T - 1) {                            // trailing empty segments
            for (int t = s + 1; t < B; ++t)
                __builtin_nontemporal_store(wv, &out[(T + t) * V4 + lane]);
        }
    }
}

extern "C" void kernel_launch(void* const* d_in, const int* in_sizes, int n_in,
                              void* d_out, int out_size, void* d_ws, size_t ws_size,
                              hipStream_t stream) {
    const float* x_flat = (const float*)d_in[0];
    const float* weight = (const float*)d_in[1];
    const int*   seg    = (const int*)d_in[2];
    // num_segments (d_in[3]) is a device scalar; derive B from sizes instead
    // (graph-capture safe, no readback):
    const int T = in_sizes[2];                 // seg_ids element count
    const int B = out_size / DTOK - T;         // out rows = T + B

    // 2048 blocks x 256 threads = 8192 waves, ~32 rows/wave grid-stride.
    ctn_fused<<<2048, 256, 0, stream>>>(
        (const f4*)x_flat, seg, (const f4*)weight,
        (f4*)d_out, T, B);
}